// Round 7
// baseline (1549.243 us; speedup 1.0000x reference)
//
#include <hip/hip_runtime.h>
#include <cstdint>
#include <cstddef>

#define DIM 256
#define SLOPE 0.2f
#define BSHIFT 8          // 256 rows per bucket
#define SLOTS 9216        // per-bucket capacity: mean 8192 + ~11 sigma slack
#define TILE 4096         // edges per bin_edges block

typedef __attribute__((ext_vector_type(8))) short short8;           // 8 bf16
typedef __attribute__((ext_vector_type(8))) unsigned short ushort8; // 16 B gather
typedef __attribute__((ext_vector_type(4))) float f32x4;            // 4 fp32 acc

__device__ __forceinline__ unsigned short f2bf(float f) {  // RNE fp32->bf16
  unsigned u = __float_as_uint(f);
  u += 0x7fffu + ((u >> 16) & 1u);
  return (unsigned short)(u >> 16);
}
__device__ __forceinline__ float bf2f(unsigned short h) {
  return __uint_as_float(((unsigned)h) << 16);
}

// Wt[t][n][k] = bf16(W_t[k][n]) ; grid (256, 3), 256 threads
__global__ void wtrans_kernel(const float* __restrict__ W0, const float* __restrict__ W1,
                              const float* __restrict__ W2, unsigned short* __restrict__ Wt) {
  const float* W = blockIdx.y == 0 ? W0 : (blockIdx.y == 1 ? W1 : W2);
  int k = blockIdx.x, n = threadIdx.x;
  Wt[((size_t)blockIdx.y * DIM + n) * DIM + k] = f2bf(W[k * DIM + n]);
}

// 64-row tile / block (256 thr = 4 waves). Whole K=256 staged in LDS as bf16.
// (round-3 verified version: separate Os, launch_bounds(256,2))
__global__ __launch_bounds__(256, 2) void gemm_scores_kernel(
    const float* __restrict__ H, const unsigned short* __restrict__ Wt,
    const float* __restrict__ a, unsigned short* __restrict__ Whb,
    float* __restrict__ s_dst, float* __restrict__ s_src, int N) {
  __shared__ unsigned short Hs[64][264];      // +8 pad
  __shared__ unsigned short Os[4][16][264];   // per-wave store staging
  const int t = threadIdx.x;
  const int r0 = blockIdx.x * 64;
#pragma unroll
  for (int i = 0; i < 16; ++i) {
    int idx = t + i * 256;
    int row = idx >> 6;
    int c4 = idx & 63;
    int r = r0 + row;
    float4 h = (r < N) ? *(const float4*)&H[(size_t)r * DIM + c4 * 4]
                       : make_float4(0.f, 0.f, 0.f, 0.f);
    unsigned lo = (unsigned)f2bf(h.x) | ((unsigned)f2bf(h.y) << 16);
    unsigned hi = (unsigned)f2bf(h.z) | ((unsigned)f2bf(h.w) << 16);
    *(uint2*)&Hs[row][c4 * 4] = make_uint2(lo, hi);
  }
  __syncthreads();
  const int wave = t >> 6, lane = t & 63;
  const int q = lane >> 4, m = lane & 15;
  const int rowbase = wave * 16;
  short8 Af[8];
#pragma unroll
  for (int k0 = 0; k0 < 8; ++k0)
    Af[k0] = *(const short8*)&Hs[rowbase + m][k0 * 32 + q * 8];
  f32x4 acc[16];
#pragma unroll
  for (int j = 0; j < 16; ++j) acc[j] = (f32x4){0.f, 0.f, 0.f, 0.f};
#pragma unroll
  for (int k0 = 0; k0 < 8; ++k0) {
#pragma unroll
    for (int j = 0; j < 16; ++j) {
      short8 Bf = *(const short8*)&Wt[(size_t)(j * 16 + m) * DIM + k0 * 32 + q * 8];
      acc[j] = __builtin_amdgcn_mfma_f32_16x16x32_bf16(Af[k0], Bf, acc[j], 0, 0, 0);
    }
  }
  float pd[4] = {0, 0, 0, 0}, ps[4] = {0, 0, 0, 0};
#pragma unroll
  for (int j = 0; j < 16; ++j) {
    int col = j * 16 + m;
    float ad = a[col], as = a[DIM + col];
#pragma unroll
    for (int reg = 0; reg < 4; ++reg) {
      float v = acc[j][reg];  // row = q*4+reg, col
      pd[reg] += v * ad;
      ps[reg] += v * as;
      Os[wave][q * 4 + reg][col] = f2bf(v);
    }
  }
#pragma unroll
  for (int off = 8; off >= 1; off >>= 1) {
#pragma unroll
    for (int reg = 0; reg < 4; ++reg) {
      pd[reg] += __shfl_down(pd[reg], off);
      ps[reg] += __shfl_down(ps[reg], off);
    }
  }
  if (m == 0) {
#pragma unroll
    for (int reg = 0; reg < 4; ++reg) {
      int r = r0 + rowbase + q * 4 + reg;
      if (r < N) {
        s_dst[r] = pd[reg];
        s_src[r] = ps[reg];
      }
    }
  }
  __syncthreads();
#pragma unroll
  for (int row = 0; row < 16; ++row) {
    int r = r0 + rowbase + row;
    if (r < N)
      *(uint2*)&Whb[(size_t)r * DIM + lane * 4] = *(const uint2*)&Os[wave][row][lane * 4];
  }
}

// ---- CSR build via two-level bucket partition --------------------------------
__global__ __launch_bounds__(256) void bin_edges_kernel(
    const int* __restrict__ r0, const int* __restrict__ r1, const int* __restrict__ r2,
    const int* __restrict__ c0, const int* __restrict__ c1, const int* __restrict__ c2,
    int* __restrict__ bcnt,        // [3*NB], zero-initialized
    unsigned* __restrict__ pairs,  // [3*NB*SLOTS]
    int E, int NB) {
  __shared__ int hist[512];  // NB=391 <= 512
  __shared__ int curs[512];
  const int ty = blockIdx.y;
  const int* rr = ty == 0 ? r0 : (ty == 1 ? r1 : r2);
  const int* cc = ty == 0 ? c0 : (ty == 1 ? c1 : c2);
  const int t = threadIdx.x;
  const int base = blockIdx.x * TILE;
  for (int i = t; i < NB; i += 256) hist[i] = 0;
  __syncthreads();
  int rows[TILE / 256];
#pragma unroll
  for (int i = 0; i < TILE / 256; ++i) {
    int e = base + t + i * 256;
    int r = (e < E) ? rr[e] : -1;
    rows[i] = r;
    if (r >= 0) atomicAdd(&hist[r >> BSHIFT], 1);
  }
  __syncthreads();
  for (int b = t; b < NB; b += 256) {
    int h = hist[b];
    int off = h ? atomicAdd(&bcnt[ty * NB + b], h) : 0;
    curs[b] = b * SLOTS + off;  // absolute index within this type's slab
  }
  __syncthreads();
  unsigned* pt = pairs + (size_t)ty * NB * SLOTS;
#pragma unroll
  for (int i = 0; i < TILE / 256; ++i) {
    int e = base + t + i * 256;
    if (e >= E) continue;
    int r = rows[i];
    int b = r >> BSHIFT;
    int pos = atomicAdd(&curs[b], 1);
    if (pos - b * SLOTS < SLOTS)  // overflow guard (statistically unreachable)
      pt[pos] = ((unsigned)(r & 255) << 17) | (unsigned)cc[e];
  }
}

// Level 2: one block per (bucket,type). In-LDS counting sort (row-only key);
// emits rp/deg.
__global__ __launch_bounds__(256) void bucket_sort_kernel(
    const int* __restrict__ bcnt, unsigned* __restrict__ pairs,
    int* __restrict__ rp, int* __restrict__ deg, int N, int NB) {
  __shared__ int hist[256];
  __shared__ int excl[256];
  __shared__ int curs[256];
  __shared__ unsigned stage[SLOTS];
  const int b = blockIdx.x, ty = blockIdx.y;
  const int t = threadIdx.x;
  int cnt = bcnt[ty * NB + b];
  if (cnt > SLOTS) cnt = SLOTS;
  unsigned* pb = pairs + (size_t)ty * NB * SLOTS + (size_t)b * SLOTS;
  hist[t] = 0;
  __syncthreads();
  for (int i = t; i < cnt; i += 256) atomicAdd(&hist[pb[i] >> 17], 1);
  __syncthreads();
  int v = hist[t];
  excl[t] = v;
  __syncthreads();
  for (int off = 1; off < 256; off <<= 1) {
    int u = (t >= off) ? excl[t - off] : 0;
    __syncthreads();
    excl[t] += u;
    __syncthreads();
  }
  int ex = excl[t] - v;  // exclusive scan
  curs[t] = ex;
  int r = (b << BSHIFT) + t;
  if (r < N) {
    rp[(size_t)ty * N + r] = b * SLOTS + ex;
    deg[(size_t)ty * N + r] = v;
  }
  __syncthreads();
  for (int i = t; i < cnt; i += 256) {
    unsigned p = pb[i];
    int pos = atomicAdd(&curs[p >> 17], 1);
    stage[pos] = p;
  }
  __syncthreads();
  for (int i = t; i < cnt; i += 256) pb[i] = stage[i];
}

// FUSED gat: one wave per destination node, all 3 types, single out write.
// v3: half-wave gathers (lanes 0-31 edge j, lanes 32-63 edge j+1; 16 B/lane)
// -> 1 KB per gather instruction; single-pass softmax for d<=64 (the ~100%
// case at mean degree 32): (col,v) kept in the lane's registers, wave-reduce
// max, exp in place -- no second pcol/s_src pass.
__global__ __launch_bounds__(256) void gat_fused_kernel(
    const int* __restrict__ rp, const int* __restrict__ deg,
    const unsigned* __restrict__ pairs,
    const float* __restrict__ s_dst, const float* __restrict__ s_src,
    const unsigned short* __restrict__ Whb,
    const float* __restrict__ bias, float* __restrict__ out, int N, int NB) {
  __shared__ uint2 ebuf[4][65];  // per-wave parked (col, exp-weight)
  int n = (int)((blockIdx.x * (unsigned)blockDim.x + threadIdx.x) >> 6);
  if (n >= N) return;
  const int wid = (threadIdx.x >> 6);
  const int lane = threadIdx.x & 63;
  const int half = lane >> 5;       // 0: even edges, 1: odd edges
  const int sub = lane & 31;        // 16B slot within the row
  const size_t NDIM = (size_t)N * DIM;
  float total[8];
#pragma unroll
  for (int k = 0; k < 8; ++k) total[k] = 0.f;
  for (int t = 0; t < 3; ++t) {
    int beg = rp[(size_t)t * N + n], d = deg[(size_t)t * N + n];
    if (d == 0) continue;
    const unsigned* pcol = pairs + (size_t)t * NB * SLOTS;
    const float* ss = s_src + (size_t)t * N;
    float sd = s_dst[(size_t)t * N + n];
    const unsigned short* wb = Whb + (size_t)t * NDIM + sub * 8;
    float acc[8];
#pragma unroll
    for (int k = 0; k < 8; ++k) acc[k] = 0.f;
    float psum = 0.f;
    if (d <= 64) {
      // single pass: lane owns one edge
      unsigned myc = 0;
      float v = -__builtin_inff();
      if (lane < d) {
        myc = pcol[beg + lane] & 0x1FFFFu;
        float s = sd + ss[myc];
        v = s > 0.f ? s : SLOPE * s;
      }
      float mx = v;
#pragma unroll
      for (int off = 32; off >= 1; off >>= 1) mx = fmaxf(mx, __shfl_down(mx, off));
      mx = __shfl(mx, 0);
      float mype = (lane < d) ? __expf(v - mx) : 0.f;
      psum = mype;
      ebuf[wid][lane] = make_uint2(myc, __float_as_uint(mype));
      // same-wave LDS RAW: compiler inserts lgkmcnt
#pragma unroll 8
      for (int j = 0; j < d; j += 2) {
        uint2 cp = ebuf[wid][j + half];  // uniform per half-wave: broadcast
        float pe = __uint_as_float(cp.y);
        ushort8 w = *(const ushort8*)&wb[(size_t)cp.x * DIM];
#pragma unroll
        for (int k = 0; k < 8; ++k) acc[k] += pe * bf2f(w[k]);
      }
    } else {
      // rare path: two-pass
      int end = beg + d;
      float mx = -__builtin_inff();
      for (int p = beg + lane; p < end; p += 64) {
        float s = sd + ss[pcol[p] & 0x1FFFFu];
        s = s > 0.f ? s : SLOPE * s;
        mx = fmaxf(mx, s);
      }
#pragma unroll
      for (int off = 32; off >= 1; off >>= 1) mx = fmaxf(mx, __shfl_down(mx, off));
      mx = __shfl(mx, 0);
      for (int base = beg; base < end; base += 64) {
        int myp = base + lane;
        int cnt = end - base;
        if (cnt > 64) cnt = 64;
        unsigned myc = 0;
        float mype = 0.f;
        if (myp < end) {
          myc = pcol[myp] & 0x1FFFFu;
          float s = sd + ss[myc];
          s = s > 0.f ? s : SLOPE * s;
          mype = __expf(s - mx);
        }
        psum += mype;
        ebuf[wid][lane] = make_uint2(myc, __float_as_uint(mype));
#pragma unroll 8
        for (int j = 0; j < cnt; j += 2) {
          uint2 cp = ebuf[wid][j + half];
          float pe = __uint_as_float(cp.y);
          ushort8 w = *(const ushort8*)&wb[(size_t)cp.x * DIM];
#pragma unroll
          for (int k = 0; k < 8; ++k) acc[k] += pe * bf2f(w[k]);
        }
      }
    }
#pragma unroll
    for (int off = 32; off >= 1; off >>= 1) psum += __shfl_down(psum, off);
    psum = __shfl(psum, 0);
    float inv = 1.f / fmaxf(psum, 1e-12f);
#pragma unroll
    for (int k = 0; k < 8; ++k) total[k] += acc[k] * inv;
  }
  // merge even/odd-edge halves: lane l and l^32 hold the same 8 dims
#pragma unroll
  for (int k = 0; k < 8; ++k) total[k] += __shfl_xor(total[k], 32);
  // write: lane covers dims sub*8 + half*4 .. +3 (full 1KB row covered)
  int db = sub * 8 + half * 4;
  float4 bv = *(const float4*)&bias[db];
  float4 cur;
  cur.x = bv.x + total[half * 4 + 0];
  cur.y = bv.y + total[half * 4 + 1];
  cur.z = bv.z + total[half * 4 + 2];
  cur.w = bv.w + total[half * 4 + 3];
  *(float4*)&out[(size_t)n * DIM + db] = cur;
}

// per-type kernel (fallback path when workspace is small) — round-3 verified
__global__ __launch_bounds__(256) void gat_node_kernel(
    const int* __restrict__ rp, const int* __restrict__ deg,
    const unsigned* __restrict__ pcol,
    const float* __restrict__ s_dst, const float* __restrict__ s_src,
    const unsigned short* __restrict__ Whb,
    const float* __restrict__ bias, float* __restrict__ out, int N, int first) {
  __shared__ uint2 ebuf[4][64];
  int n = (int)((blockIdx.x * (unsigned)blockDim.x + threadIdx.x) >> 6);
  if (n >= N) return;
  const int wid = (threadIdx.x >> 6);
  const int lane = threadIdx.x & 63;
  int beg = rp[n], d = deg[n], end = beg + d;
  if (!first && d == 0) return;
  float sd = s_dst[n];
  float mx = -__builtin_inff();
  for (int p = beg + lane; p < end; p += 64) {
    float v = sd + s_src[pcol[p] & 0x1FFFFu];
    v = v > 0.f ? v : SLOPE * v;
    mx = fmaxf(mx, v);
  }
#pragma unroll
  for (int off = 32; off >= 1; off >>= 1) mx = fmaxf(mx, __shfl_down(mx, off));
  mx = __shfl(mx, 0);
  const unsigned short* wbase = Whb + lane * 4;
  float4 acc = {0.f, 0.f, 0.f, 0.f};
  float psum = 0.f;
  for (int base = beg; base < end; base += 64) {
    int myp = base + lane;
    int cnt = end - base;
    if (cnt > 64) cnt = 64;
    unsigned myc = 0;
    float mype = 0.f;
    if (myp < end) {
      myc = pcol[myp] & 0x1FFFFu;
      float v = sd + s_src[myc];
      v = v > 0.f ? v : SLOPE * v;
      mype = __expf(v - mx);
    }
    psum += mype;
    ebuf[wid][lane] = make_uint2(myc, __float_as_uint(mype));
#pragma unroll 8
    for (int j = 0; j < cnt; ++j) {
      uint2 cp = ebuf[wid][j];
      float pe = __uint_as_float(cp.y);
      ushort4 w = *(const ushort4*)&wbase[(size_t)cp.x * DIM];
      acc.x += pe * bf2f(w.x);
      acc.y += pe * bf2f(w.y);
      acc.z += pe * bf2f(w.z);
      acc.w += pe * bf2f(w.w);
    }
  }
#pragma unroll
  for (int off = 32; off >= 1; off >>= 1) psum += __shfl_down(psum, off);
  psum = __shfl(psum, 0);
  float inv = 1.f / fmaxf(psum, 1e-12f);
  float4* o = (float4*)(out + (size_t)n * DIM) + lane;
  float4 cur = first ? ((const float4*)bias)[lane] : *o;
  cur.x += acc.x * inv;
  cur.y += acc.y * inv;
  cur.z += acc.z * inv;
  cur.w += acc.w * inv;
  *o = cur;
}

static inline size_t align256(size_t x) { return (x + 255) & ~(size_t)255; }

extern "C" void kernel_launch(void* const* d_in, const int* in_sizes, int n_in,
                              void* d_out, int out_size, void* d_ws, size_t ws_size,
                              hipStream_t stream) {
  const float* H = (const float*)d_in[0];
  const float* W[3] = {(const float*)d_in[1], (const float*)d_in[2], (const float*)d_in[3]};
  const float* a[3] = {(const float*)d_in[4], (const float*)d_in[5], (const float*)d_in[6]};
  const float* bias = (const float*)d_in[7];
  const int* row[3] = {(const int*)d_in[8], (const int*)d_in[10], (const int*)d_in[12]};
  const int* col[3] = {(const int*)d_in[9], (const int*)d_in[11], (const int*)d_in[13]};
  const int N = in_sizes[0] / DIM;
  const int E = in_sizes[8];
  const int NB = (N + 255) >> BSHIFT;  // 391 for N=100000 (must be <= 512)
  float* out = (float*)d_out;

  // workspace layout: fixed part first, Whb (1x or 3x) last
  char* ws = (char*)d_ws;
  size_t off = 0;
  unsigned short* Wt = (unsigned short*)(ws + off);
  off = align256(off + (size_t)3 * DIM * DIM * sizeof(unsigned short));
  float* s_dst = (float*)(ws + off);  // [3][N]
  off = align256(off + (size_t)3 * N * sizeof(float));
  float* s_src = (float*)(ws + off);  // [3][N]
  off = align256(off + (size_t)3 * N * sizeof(float));
  int* bcnt = (int*)(ws + off);
  off = align256(off + (size_t)3 * NB * sizeof(int));
  int* rp = (int*)(ws + off);
  off = align256(off + (size_t)3 * N * sizeof(int));
  int* deg = (int*)(ws + off);
  off = align256(off + (size_t)3 * N * sizeof(int));
  unsigned* pairs = (unsigned*)(ws + off);
  off = align256(off + (size_t)3 * NB * SLOTS * sizeof(unsigned));
  unsigned short* Whb = (unsigned short*)(ws + off);
  const size_t whb_bytes = align256((size_t)N * DIM * sizeof(unsigned short));
  const int fused = (ws_size >= off + 3 * whb_bytes) ? 1 : 0;

  wtrans_kernel<<<dim3(DIM, 3), 256, 0, stream>>>(W[0], W[1], W[2], Wt);
  hipMemsetAsync(bcnt, 0, (size_t)3 * NB * sizeof(int), stream);
  const int eb = (E + TILE - 1) / TILE;
  bin_edges_kernel<<<dim3(eb, 3), 256, 0, stream>>>(row[0], row[1], row[2], col[0], col[1],
                                                    col[2], bcnt, pairs, E, NB);
  bucket_sort_kernel<<<dim3(NB, 3), 256, 0, stream>>>(bcnt, pairs, rp, deg, N, NB);

  const int gemm_blocks = (N + 63) / 64;
  const int gat_blocks = (N * 64 + 255) / 256;
  if (fused) {
    for (int t = 0; t < 3; ++t)
      gemm_scores_kernel<<<gemm_blocks, 256, 0, stream>>>(
          H, Wt + (size_t)t * DIM * DIM, a[t],
          Whb + t * (whb_bytes / sizeof(unsigned short)),
          s_dst + (size_t)t * N, s_src + (size_t)t * N, N);
    gat_fused_kernel<<<gat_blocks, 256, 0, stream>>>(rp, deg, pairs, s_dst, s_src, Whb, bias,
                                                     out, N, NB);
  } else {
    for (int t = 0; t < 3; ++t) {
      gemm_scores_kernel<<<gemm_blocks, 256, 0, stream>>>(H, Wt + (size_t)t * DIM * DIM, a[t],
                                                          Whb, s_dst + (size_t)t * N,
                                                          s_src + (size_t)t * N, N);
      gat_node_kernel<<<gat_blocks, 256, 0, stream>>>(
          rp + (size_t)t * N, deg + (size_t)t * N, pairs + (size_t)t * NB * SLOTS,
          s_dst + (size_t)t * N, s_src + (size_t)t * N, Whb, bias, out, N, t == 0 ? 1 : 0);
    }
  }
  (void)n_in;
  (void)out_size;
  (void)ws_size;
}

// Round 8
// 1532.082 us; speedup vs baseline: 1.0112x; 1.0112x over previous
//
#include <hip/hip_runtime.h>
#include <cstdint>
#include <cstddef>

#define DIM 256
#define SLOPE 0.2f
#define BSHIFT 8          // 256 rows per bucket
#define SLOTS 9216        // per-bucket capacity: mean 8192 + ~11 sigma slack
#define TILE 4096         // edges per bin_edges block

typedef __attribute__((ext_vector_type(8))) short short8;  // 8 bf16 (4 VGPRs)
typedef __attribute__((ext_vector_type(4))) float f32x4;   // 4 fp32 acc

__device__ __forceinline__ unsigned short f2bf(float f) {  // RNE fp32->bf16
  unsigned u = __float_as_uint(f);
  u += 0x7fffu + ((u >> 16) & 1u);
  return (unsigned short)(u >> 16);
}
__device__ __forceinline__ float bf2f(unsigned short h) {
  return __uint_as_float(((unsigned)h) << 16);
}

// Wt[t][n][k] = bf16(W_t[k][n]) ; grid (256, 3), 256 threads
__global__ void wtrans_kernel(const float* __restrict__ W0, const float* __restrict__ W1,
                              const float* __restrict__ W2, unsigned short* __restrict__ Wt) {
  const float* W = blockIdx.y == 0 ? W0 : (blockIdx.y == 1 ? W1 : W2);
  int k = blockIdx.x, n = threadIdx.x;
  Wt[((size_t)blockIdx.y * DIM + n) * DIM + k] = f2bf(W[k * DIM + n]);
}

// FUSED 3-type GEMM: stage H tile once, run all 3 K-loops on it.
// Af fragments are type-independent (loaded once); acc/Os reused per type.
// Os is wave-private -> no barriers needed after the staging sync.
__global__ __launch_bounds__(256, 2) void gemm3_scores_kernel(
    const float* __restrict__ H, const unsigned short* __restrict__ Wt,
    const float* __restrict__ a0, const float* __restrict__ a1,
    const float* __restrict__ a2, unsigned short* __restrict__ Whb,
    float* __restrict__ s_dst, float* __restrict__ s_src, int N, size_t wstride) {
  __shared__ unsigned short Hs[64][264];      // +8 pad
  __shared__ unsigned short Os[4][16][264];   // per-wave store staging
  const int t = threadIdx.x;
  const int r0 = blockIdx.x * 64;
#pragma unroll
  for (int i = 0; i < 16; ++i) {
    int idx = t + i * 256;
    int row = idx >> 6;
    int c4 = idx & 63;
    int r = r0 + row;
    float4 h = (r < N) ? *(const float4*)&H[(size_t)r * DIM + c4 * 4]
                       : make_float4(0.f, 0.f, 0.f, 0.f);
    unsigned lo = (unsigned)f2bf(h.x) | ((unsigned)f2bf(h.y) << 16);
    unsigned hi = (unsigned)f2bf(h.z) | ((unsigned)f2bf(h.w) << 16);
    *(uint2*)&Hs[row][c4 * 4] = make_uint2(lo, hi);
  }
  __syncthreads();
  const int wave = t >> 6, lane = t & 63;
  const int q = lane >> 4, m = lane & 15;
  const int rowbase = wave * 16;
  short8 Af[8];
#pragma unroll
  for (int k0 = 0; k0 < 8; ++k0)
    Af[k0] = *(const short8*)&Hs[rowbase + m][k0 * 32 + q * 8];
  const float* aptr[3] = {a0, a1, a2};
#pragma unroll
  for (int ty = 0; ty < 3; ++ty) {
    const unsigned short* Wtt = Wt + (size_t)ty * DIM * DIM;
    const float* a = aptr[ty];
    f32x4 acc[16];
#pragma unroll
    for (int j = 0; j < 16; ++j) acc[j] = (f32x4){0.f, 0.f, 0.f, 0.f};
#pragma unroll
    for (int k0 = 0; k0 < 8; ++k0) {
#pragma unroll
      for (int j = 0; j < 16; ++j) {
        short8 Bf = *(const short8*)&Wtt[(size_t)(j * 16 + m) * DIM + k0 * 32 + q * 8];
        acc[j] = __builtin_amdgcn_mfma_f32_16x16x32_bf16(Af[k0], Bf, acc[j], 0, 0, 0);
      }
    }
    float pd[4] = {0, 0, 0, 0}, ps[4] = {0, 0, 0, 0};
#pragma unroll
    for (int j = 0; j < 16; ++j) {
      int col = j * 16 + m;
      float ad = a[col], as = a[DIM + col];
#pragma unroll
      for (int reg = 0; reg < 4; ++reg) {
        float v = acc[j][reg];  // row = q*4+reg, col
        pd[reg] += v * ad;
        ps[reg] += v * as;
        Os[wave][q * 4 + reg][col] = f2bf(v);
      }
    }
#pragma unroll
    for (int off = 8; off >= 1; off >>= 1) {
#pragma unroll
      for (int reg = 0; reg < 4; ++reg) {
        pd[reg] += __shfl_down(pd[reg], off);
        ps[reg] += __shfl_down(ps[reg], off);
      }
    }
    if (m == 0) {
#pragma unroll
      for (int reg = 0; reg < 4; ++reg) {
        int r = r0 + rowbase + q * 4 + reg;
        if (r < N) {
          s_dst[(size_t)ty * N + r] = pd[reg];
          s_src[(size_t)ty * N + r] = ps[reg];
        }
      }
    }
    // Os[wave] is wave-private: same-wave LDS ordering suffices (no barrier)
    unsigned short* wout = Whb + (size_t)ty * wstride;
#pragma unroll
    for (int row = 0; row < 16; ++row) {
      int r = r0 + rowbase + row;
      if (r < N)
        *(uint2*)&wout[(size_t)r * DIM + lane * 4] = *(const uint2*)&Os[wave][row][lane * 4];
    }
  }
}

// per-type gemm (fallback path) — round-3 verified
__global__ __launch_bounds__(256, 2) void gemm_scores_kernel(
    const float* __restrict__ H, const unsigned short* __restrict__ Wt,
    const float* __restrict__ a, unsigned short* __restrict__ Whb,
    float* __restrict__ s_dst, float* __restrict__ s_src, int N) {
  __shared__ unsigned short Hs[64][264];
  __shared__ unsigned short Os[4][16][264];
  const int t = threadIdx.x;
  const int r0 = blockIdx.x * 64;
#pragma unroll
  for (int i = 0; i < 16; ++i) {
    int idx = t + i * 256;
    int row = idx >> 6;
    int c4 = idx & 63;
    int r = r0 + row;
    float4 h = (r < N) ? *(const float4*)&H[(size_t)r * DIM + c4 * 4]
                       : make_float4(0.f, 0.f, 0.f, 0.f);
    unsigned lo = (unsigned)f2bf(h.x) | ((unsigned)f2bf(h.y) << 16);
    unsigned hi = (unsigned)f2bf(h.z) | ((unsigned)f2bf(h.w) << 16);
    *(uint2*)&Hs[row][c4 * 4] = make_uint2(lo, hi);
  }
  __syncthreads();
  const int wave = t >> 6, lane = t & 63;
  const int q = lane >> 4, m = lane & 15;
  const int rowbase = wave * 16;
  short8 Af[8];
#pragma unroll
  for (int k0 = 0; k0 < 8; ++k0)
    Af[k0] = *(const short8*)&Hs[rowbase + m][k0 * 32 + q * 8];
  f32x4 acc[16];
#pragma unroll
  for (int j = 0; j < 16; ++j) acc[j] = (f32x4){0.f, 0.f, 0.f, 0.f};
#pragma unroll
  for (int k0 = 0; k0 < 8; ++k0) {
#pragma unroll
    for (int j = 0; j < 16; ++j) {
      short8 Bf = *(const short8*)&Wt[(size_t)(j * 16 + m) * DIM + k0 * 32 + q * 8];
      acc[j] = __builtin_amdgcn_mfma_f32_16x16x32_bf16(Af[k0], Bf, acc[j], 0, 0, 0);
    }
  }
  float pd[4] = {0, 0, 0, 0}, ps[4] = {0, 0, 0, 0};
#pragma unroll
  for (int j = 0; j < 16; ++j) {
    int col = j * 16 + m;
    float ad = a[col], as = a[DIM + col];
#pragma unroll
    for (int reg = 0; reg < 4; ++reg) {
      float v = acc[j][reg];
      pd[reg] += v * ad;
      ps[reg] += v * as;
      Os[wave][q * 4 + reg][col] = f2bf(v);
    }
  }
#pragma unroll
  for (int off = 8; off >= 1; off >>= 1) {
#pragma unroll
    for (int reg = 0; reg < 4; ++reg) {
      pd[reg] += __shfl_down(pd[reg], off);
      ps[reg] += __shfl_down(ps[reg], off);
    }
  }
  if (m == 0) {
#pragma unroll
    for (int reg = 0; reg < 4; ++reg) {
      int r = r0 + rowbase + q * 4 + reg;
      if (r < N) {
        s_dst[r] = pd[reg];
        s_src[r] = ps[reg];
      }
    }
  }
  __syncthreads();
#pragma unroll
  for (int row = 0; row < 16; ++row) {
    int r = r0 + rowbase + row;
    if (r < N)
      *(uint2*)&Whb[(size_t)r * DIM + lane * 4] = *(const uint2*)&Os[wave][row][lane * 4];
  }
}

// ---- CSR build via two-level bucket partition --------------------------------
__global__ __launch_bounds__(256) void bin_edges_kernel(
    const int* __restrict__ r0, const int* __restrict__ r1, const int* __restrict__ r2,
    const int* __restrict__ c0, const int* __restrict__ c1, const int* __restrict__ c2,
    int* __restrict__ bcnt,        // [3*NB], zero-initialized
    unsigned* __restrict__ pairs,  // [3*NB*SLOTS]
    int E, int NB) {
  __shared__ int hist[512];  // NB=391 <= 512
  __shared__ int curs[512];
  const int ty = blockIdx.y;
  const int* rr = ty == 0 ? r0 : (ty == 1 ? r1 : r2);
  const int* cc = ty == 0 ? c0 : (ty == 1 ? c1 : c2);
  const int t = threadIdx.x;
  const int base = blockIdx.x * TILE;
  for (int i = t; i < NB; i += 256) hist[i] = 0;
  __syncthreads();
  int rows[TILE / 256];
#pragma unroll
  for (int i = 0; i < TILE / 256; ++i) {
    int e = base + t + i * 256;
    int r = (e < E) ? rr[e] : -1;
    rows[i] = r;
    if (r >= 0) atomicAdd(&hist[r >> BSHIFT], 1);
  }
  __syncthreads();
  for (int b = t; b < NB; b += 256) {
    int h = hist[b];
    int off = h ? atomicAdd(&bcnt[ty * NB + b], h) : 0;
    curs[b] = b * SLOTS + off;  // absolute index within this type's slab
  }
  __syncthreads();
  unsigned* pt = pairs + (size_t)ty * NB * SLOTS;
#pragma unroll
  for (int i = 0; i < TILE / 256; ++i) {
    int e = base + t + i * 256;
    if (e >= E) continue;
    int r = rows[i];
    int b = r >> BSHIFT;
    int pos = atomicAdd(&curs[b], 1);
    if (pos - b * SLOTS < SLOTS)  // overflow guard (statistically unreachable)
      pt[pos] = ((unsigned)(r & 255) << 17) | (unsigned)cc[e];
  }
}

// Level 2: one block per (bucket,type). In-LDS counting sort (row key);
// emits rp/deg.
__global__ __launch_bounds__(256) void bucket_sort_kernel(
    const int* __restrict__ bcnt, unsigned* __restrict__ pairs,
    int* __restrict__ rp, int* __restrict__ deg, int N, int NB) {
  __shared__ int hist[256];
  __shared__ int excl[256];
  __shared__ int curs[256];
  __shared__ unsigned stage[SLOTS];
  const int b = blockIdx.x, ty = blockIdx.y;
  const int t = threadIdx.x;
  int cnt = bcnt[ty * NB + b];
  if (cnt > SLOTS) cnt = SLOTS;
  unsigned* pb = pairs + (size_t)ty * NB * SLOTS + (size_t)b * SLOTS;
  hist[t] = 0;
  __syncthreads();
  for (int i = t; i < cnt; i += 256) atomicAdd(&hist[pb[i] >> 17], 1);
  __syncthreads();
  int v = hist[t];
  excl[t] = v;
  __syncthreads();
  for (int off = 1; off < 256; off <<= 1) {
    int u = (t >= off) ? excl[t - off] : 0;
    __syncthreads();
    excl[t] += u;
    __syncthreads();
  }
  int ex = excl[t] - v;  // exclusive scan
  curs[t] = ex;
  int r = (b << BSHIFT) + t;
  if (r < N) {
    rp[(size_t)ty * N + r] = b * SLOTS + ex;
    deg[(size_t)ty * N + r] = v;
  }
  __syncthreads();
  for (int i = t; i < cnt; i += 256) {
    unsigned p = pb[i];
    int pos = atomicAdd(&curs[p >> 17], 1);
    stage[pos] = p;
  }
  __syncthreads();
  for (int i = t; i < cnt; i += 256) pb[i] = stage[i];
}

// FUSED gat (round-5 verified best): one wave per destination node, all 3
// types in-register, single out write (bias folded).
__global__ __launch_bounds__(256) void gat_fused_kernel(
    const int* __restrict__ rp, const int* __restrict__ deg,
    const unsigned* __restrict__ pairs,
    const float* __restrict__ s_dst, const float* __restrict__ s_src,
    const unsigned short* __restrict__ Whb,
    const float* __restrict__ bias, float* __restrict__ out, int N, int NB,
    size_t wstride) {
  __shared__ uint2 ebuf[4][64];  // per-wave parked (col, exp-weight)
  int n = (int)((blockIdx.x * (unsigned)blockDim.x + threadIdx.x) >> 6);
  if (n >= N) return;
  const int wid = (threadIdx.x >> 6);
  const int lane = threadIdx.x & 63;
  float4 total = {0.f, 0.f, 0.f, 0.f};
  for (int t = 0; t < 3; ++t) {
    int beg = rp[(size_t)t * N + n], d = deg[(size_t)t * N + n];
    if (d == 0) continue;
    int end = beg + d;
    const unsigned* pcol = pairs + (size_t)t * NB * SLOTS;
    const float* ss = s_src + (size_t)t * N;
    float sd = s_dst[(size_t)t * N + n];
    const unsigned short* wbase = Whb + (size_t)t * wstride + lane * 4;
    // pass A: segment max (lane-parallel)
    float mx = -__builtin_inff();
    for (int p = beg + lane; p < end; p += 64) {
      float v = sd + ss[pcol[p] & 0x1FFFFu];
      v = v > 0.f ? v : SLOPE * v;
      mx = fmaxf(mx, v);
    }
#pragma unroll
    for (int off = 32; off >= 1; off >>= 1) mx = fmaxf(mx, __shfl_down(mx, off));
    mx = __shfl(mx, 0);
    // pass B: chunk of 64 edges -> lane-parallel exp, then unrolled gather+FMA
    float4 acc = {0.f, 0.f, 0.f, 0.f};
    float psum = 0.f;
    for (int base = beg; base < end; base += 64) {
      int myp = base + lane;
      int cnt = end - base;
      if (cnt > 64) cnt = 64;
      unsigned myc = 0;
      float mype = 0.f;
      if (myp < end) {
        myc = pcol[myp] & 0x1FFFFu;
        float v = sd + ss[myc];
        v = v > 0.f ? v : SLOPE * v;
        mype = __expf(v - mx);
      }
      psum += mype;
      ebuf[wid][lane] = make_uint2(myc, __float_as_uint(mype));
      // same-wave LDS RAW: compiler inserts lgkmcnt; no barrier needed
#pragma unroll 8
      for (int j = 0; j < cnt; ++j) {
        uint2 cp = ebuf[wid][j];  // uniform addr: broadcast, conflict-free
        float pe = __uint_as_float(cp.y);
        ushort4 w = *(const ushort4*)&wbase[(size_t)cp.x * DIM];
        acc.x += pe * bf2f(w.x);
        acc.y += pe * bf2f(w.y);
        acc.z += pe * bf2f(w.z);
        acc.w += pe * bf2f(w.w);
      }
    }
#pragma unroll
    for (int off = 32; off >= 1; off >>= 1) psum += __shfl_down(psum, off);
    psum = __shfl(psum, 0);
    float inv = 1.f / fmaxf(psum, 1e-12f);
    total.x += acc.x * inv;
    total.y += acc.y * inv;
    total.z += acc.z * inv;
    total.w += acc.w * inv;
  }
  float4 cur = ((const float4*)bias)[lane];
  cur.x += total.x;
  cur.y += total.y;
  cur.z += total.z;
  cur.w += total.w;
  *((float4*)(out + (size_t)n * DIM) + lane) = cur;
}

// per-type kernel (fallback path when workspace is small) — round-3 verified
__global__ __launch_bounds__(256) void gat_node_kernel(
    const int* __restrict__ rp, const int* __restrict__ deg,
    const unsigned* __restrict__ pcol,
    const float* __restrict__ s_dst, const float* __restrict__ s_src,
    const unsigned short* __restrict__ Whb,
    const float* __restrict__ bias, float* __restrict__ out, int N, int first) {
  __shared__ uint2 ebuf[4][64];
  int n = (int)((blockIdx.x * (unsigned)blockDim.x + threadIdx.x) >> 6);
  if (n >= N) return;
  const int wid = (threadIdx.x >> 6);
  const int lane = threadIdx.x & 63;
  int beg = rp[n], d = deg[n], end = beg + d;
  if (!first && d == 0) return;
  float sd = s_dst[n];
  float mx = -__builtin_inff();
  for (int p = beg + lane; p < end; p += 64) {
    float v = sd + s_src[pcol[p] & 0x1FFFFu];
    v = v > 0.f ? v : SLOPE * v;
    mx = fmaxf(mx, v);
  }
#pragma unroll
  for (int off = 32; off >= 1; off >>= 1) mx = fmaxf(mx, __shfl_down(mx, off));
  mx = __shfl(mx, 0);
  const unsigned short* wbase = Whb + lane * 4;
  float4 acc = {0.f, 0.f, 0.f, 0.f};
  float psum = 0.f;
  for (int base = beg; base < end; base += 64) {
    int myp = base + lane;
    int cnt = end - base;
    if (cnt > 64) cnt = 64;
    unsigned myc = 0;
    float mype = 0.f;
    if (myp < end) {
      myc = pcol[myp] & 0x1FFFFu;
      float v = sd + s_src[myc];
      v = v > 0.f ? v : SLOPE * v;
      mype = __expf(v - mx);
    }
    psum += mype;
    ebuf[wid][lane] = make_uint2(myc, __float_as_uint(mype));
#pragma unroll 8
    for (int j = 0; j < cnt; ++j) {
      uint2 cp = ebuf[wid][j];
      float pe = __uint_as_float(cp.y);
      ushort4 w = *(const ushort4*)&wbase[(size_t)cp.x * DIM];
      acc.x += pe * bf2f(w.x);
      acc.y += pe * bf2f(w.y);
      acc.z += pe * bf2f(w.z);
      acc.w += pe * bf2f(w.w);
    }
  }
#pragma unroll
  for (int off = 32; off >= 1; off >>= 1) psum += __shfl_down(psum, off);
  psum = __shfl(psum, 0);
  float inv = 1.f / fmaxf(psum, 1e-12f);
  float4* o = (float4*)(out + (size_t)n * DIM) + lane;
  float4 cur = first ? ((const float4*)bias)[lane] : *o;
  cur.x += acc.x * inv;
  cur.y += acc.y * inv;
  cur.z += acc.z * inv;
  cur.w += acc.w * inv;
  *o = cur;
}

static inline size_t align256(size_t x) { return (x + 255) & ~(size_t)255; }

extern "C" void kernel_launch(void* const* d_in, const int* in_sizes, int n_in,
                              void* d_out, int out_size, void* d_ws, size_t ws_size,
                              hipStream_t stream) {
  const float* H = (const float*)d_in[0];
  const float* W[3] = {(const float*)d_in[1], (const float*)d_in[2], (const float*)d_in[3]};
  const float* a[3] = {(const float*)d_in[4], (const float*)d_in[5], (const float*)d_in[6]};
  const float* bias = (const float*)d_in[7];
  const int* row[3] = {(const int*)d_in[8], (const int*)d_in[10], (const int*)d_in[12]};
  const int* col[3] = {(const int*)d_in[9], (const int*)d_in[11], (const int*)d_in[13]};
  const int N = in_sizes[0] / DIM;
  const int E = in_sizes[8];
  const int NB = (N + 255) >> BSHIFT;  // 391 for N=100000 (must be <= 512)
  float* out = (float*)d_out;

  // workspace layout: fixed part first, Whb (1x or 3x) last
  char* ws = (char*)d_ws;
  size_t off = 0;
  unsigned short* Wt = (unsigned short*)(ws + off);
  off = align256(off + (size_t)3 * DIM * DIM * sizeof(unsigned short));
  float* s_dst = (float*)(ws + off);  // [3][N]
  off = align256(off + (size_t)3 * N * sizeof(float));
  float* s_src = (float*)(ws + off);  // [3][N]
  off = align256(off + (size_t)3 * N * sizeof(float));
  int* bcnt = (int*)(ws + off);
  off = align256(off + (size_t)3 * NB * sizeof(int));
  int* rp = (int*)(ws + off);
  off = align256(off + (size_t)3 * N * sizeof(int));
  int* deg = (int*)(ws + off);
  off = align256(off + (size_t)3 * N * sizeof(int));
  unsigned* pairs = (unsigned*)(ws + off);
  off = align256(off + (size_t)3 * NB * SLOTS * sizeof(unsigned));
  unsigned short* Whb = (unsigned short*)(ws + off);
  const size_t whb_bytes = align256((size_t)N * DIM * sizeof(unsigned short));
  const size_t wstride = whb_bytes / sizeof(unsigned short);
  const int fused = (ws_size >= off + 3 * whb_bytes) ? 1 : 0;

  wtrans_kernel<<<dim3(DIM, 3), 256, 0, stream>>>(W[0], W[1], W[2], Wt);
  hipMemsetAsync(bcnt, 0, (size_t)3 * NB * sizeof(int), stream);
  const int eb = (E + TILE - 1) / TILE;
  bin_edges_kernel<<<dim3(eb, 3), 256, 0, stream>>>(row[0], row[1], row[2], col[0], col[1],
                                                    col[2], bcnt, pairs, E, NB);
  bucket_sort_kernel<<<dim3(NB, 3), 256, 0, stream>>>(bcnt, pairs, rp, deg, N, NB);

  const int gemm_blocks = (N + 63) / 64;
  const int gat_blocks = (N * 64 + 255) / 256;
  if (fused) {
    gemm3_scores_kernel<<<gemm_blocks, 256, 0, stream>>>(H, Wt, a[0], a[1], a[2], Whb, s_dst,
                                                         s_src, N, wstride);
    gat_fused_kernel<<<gat_blocks, 256, 0, stream>>>(rp, deg, pairs, s_dst, s_src, Whb, bias,
                                                     out, N, NB, wstride);
  } else {
    for (int t = 0; t < 3; ++t) {
      gemm_scores_kernel<<<gemm_blocks, 256, 0, stream>>>(H, Wt + (size_t)t * DIM * DIM, a[t],
                                                          Whb, s_dst + (size_t)t * N,
                                                          s_src + (size_t)t * N, N);
      gat_node_kernel<<<gat_blocks, 256, 0, stream>>>(
          rp + (size_t)t * N, deg + (size_t)t * N, pairs + (size_t)t * NB * SLOTS,
          s_dst + (size_t)t * N, s_src + (size_t)t * N, Whb, bias, out, N, t == 0 ? 1 : 0);
    }
  }
  (void)n_in;
  (void)out_size;
  (void)ws_size;
}

// Round 9
// 1425.815 us; speedup vs baseline: 1.0866x; 1.0745x over previous
//
#include <hip/hip_runtime.h>
#include <cstdint>
#include <cstddef>

#define DIM 256
#define SLOPE 0.2f
#define BSHIFT 8          // 256 rows per bucket
#define SLOTS 9216        // per-bucket capacity: mean 8192 + ~11 sigma slack
#define TILE 4096         // edges per bin_edges block

typedef __attribute__((ext_vector_type(8))) short short8;  // 8 bf16 (4 VGPRs)
typedef __attribute__((ext_vector_type(4))) float f32x4;   // 4 fp32 acc

__device__ __forceinline__ unsigned short f2bf(float f) {  // RNE fp32->bf16
  unsigned u = __float_as_uint(f);
  u += 0x7fffu + ((u >> 16) & 1u);
  return (unsigned short)(u >> 16);
}
__device__ __forceinline__ float bf2f(unsigned short h) {
  return __uint_as_float(((unsigned)h) << 16);
}

// Wt[t][n][k] = bf16(W_t[k][n]) ; grid (256, 3), 256 threads
__global__ void wtrans_kernel(const float* __restrict__ W0, const float* __restrict__ W1,
                              const float* __restrict__ W2, unsigned short* __restrict__ Wt) {
  const float* W = blockIdx.y == 0 ? W0 : (blockIdx.y == 1 ? W1 : W2);
  int k = blockIdx.x, n = threadIdx.x;
  Wt[((size_t)blockIdx.y * DIM + n) * DIM + k] = f2bf(W[k * DIM + n]);
}

// FUSED 3-type GEMM v2: 128-row tile, 4 waves x 32 rows/wave.
// Each B-fragment (16B from L2) feeds TWO MFMAs (acc0/acc1) -> halves
// B-load count + latency exposure vs the 16-rows/wave version.
// LDS: Hs 67.6 KB + Os 8.4 KB (4-row store passes) = 76 KB -> 2 blocks/CU,
// 8 waves/CU (same occupancy as before). VGPR ~230 fits launch_bounds(256,2).
__global__ __launch_bounds__(256, 2) void gemm3_scores_kernel(
    const float* __restrict__ H, const unsigned short* __restrict__ Wt,
    const float* __restrict__ a0, const float* __restrict__ a1,
    const float* __restrict__ a2, unsigned short* __restrict__ Whb,
    float* __restrict__ s_dst, float* __restrict__ s_src, int N, size_t wstride) {
  __shared__ unsigned short Hs[128][264];   // +8 pad
  __shared__ unsigned short Os[4][4][264];  // per-wave 4-row store staging
  const int t = threadIdx.x;
  const int r0 = blockIdx.x * 128;
  // stage 128 rows of H as bf16: 8192 float4 chunks, 32/thread
#pragma unroll
  for (int i = 0; i < 32; ++i) {
    int idx = t + i * 256;
    int row = idx >> 6;
    int c4 = idx & 63;
    int r = r0 + row;
    float4 h = (r < N) ? *(const float4*)&H[(size_t)r * DIM + c4 * 4]
                       : make_float4(0.f, 0.f, 0.f, 0.f);
    unsigned lo = (unsigned)f2bf(h.x) | ((unsigned)f2bf(h.y) << 16);
    unsigned hi = (unsigned)f2bf(h.z) | ((unsigned)f2bf(h.w) << 16);
    *(uint2*)&Hs[row][c4 * 4] = make_uint2(lo, hi);
  }
  __syncthreads();
  const int wave = t >> 6, lane = t & 63;
  const int q = lane >> 4, m = lane & 15;
  const int rowbase = wave * 32;  // wave owns 32 rows (2 x 16-row groups)
  short8 Af0[8], Af1[8];
#pragma unroll
  for (int k0 = 0; k0 < 8; ++k0) {
    Af0[k0] = *(const short8*)&Hs[rowbase + m][k0 * 32 + q * 8];
    Af1[k0] = *(const short8*)&Hs[rowbase + 16 + m][k0 * 32 + q * 8];
  }
  const float* aptr[3] = {a0, a1, a2};
  for (int ty = 0; ty < 3; ++ty) {
    const unsigned short* Wtt = Wt + (size_t)ty * DIM * DIM;
    const float* a = aptr[ty];
    f32x4 acc0[16], acc1[16];
#pragma unroll
    for (int j = 0; j < 16; ++j) {
      acc0[j] = (f32x4){0.f, 0.f, 0.f, 0.f};
      acc1[j] = (f32x4){0.f, 0.f, 0.f, 0.f};
    }
#pragma unroll
    for (int k0 = 0; k0 < 8; ++k0) {
#pragma unroll
      for (int j = 0; j < 16; ++j) {
        short8 Bf = *(const short8*)&Wtt[(size_t)(j * 16 + m) * DIM + k0 * 32 + q * 8];
        acc0[j] = __builtin_amdgcn_mfma_f32_16x16x32_bf16(Af0[k0], Bf, acc0[j], 0, 0, 0);
        acc1[j] = __builtin_amdgcn_mfma_f32_16x16x32_bf16(Af1[k0], Bf, acc1[j], 0, 0, 0);
      }
    }
    // scores epilogue for both row groups
    float pd0[4] = {0, 0, 0, 0}, ps0[4] = {0, 0, 0, 0};
    float pd1[4] = {0, 0, 0, 0}, ps1[4] = {0, 0, 0, 0};
#pragma unroll
    for (int j = 0; j < 16; ++j) {
      int col = j * 16 + m;
      float ad = a[col], as = a[DIM + col];
#pragma unroll
      for (int reg = 0; reg < 4; ++reg) {
        float v0 = acc0[j][reg], v1 = acc1[j][reg];
        pd0[reg] += v0 * ad;
        ps0[reg] += v0 * as;
        pd1[reg] += v1 * ad;
        ps1[reg] += v1 * as;
      }
    }
#pragma unroll
    for (int off = 8; off >= 1; off >>= 1) {
#pragma unroll
      for (int reg = 0; reg < 4; ++reg) {
        pd0[reg] += __shfl_down(pd0[reg], off);
        ps0[reg] += __shfl_down(ps0[reg], off);
        pd1[reg] += __shfl_down(pd1[reg], off);
        ps1[reg] += __shfl_down(ps1[reg], off);
      }
    }
    if (m == 0) {
#pragma unroll
      for (int reg = 0; reg < 4; ++reg) {
        int ra = r0 + rowbase + q * 4 + reg;
        int rb = ra + 16;
        if (ra < N) {
          s_dst[(size_t)ty * N + ra] = pd0[reg];
          s_src[(size_t)ty * N + ra] = ps0[reg];
        }
        if (rb < N) {
          s_dst[(size_t)ty * N + rb] = pd1[reg];
          s_src[(size_t)ty * N + rb] = ps1[reg];
        }
      }
    }
    // Whb stores in 4-row passes (Os is wave-private: same-wave LDS
    // write->read ordering, no barrier needed)
    unsigned short* wout = Whb + (size_t)ty * wstride;
#pragma unroll
    for (int g = 0; g < 2; ++g) {
#pragma unroll
      for (int p = 0; p < 4; ++p) {
        if (q == p) {  // lanes holding rows p*4..p*4+3 of this group
#pragma unroll
          for (int j = 0; j < 16; ++j)
#pragma unroll
            for (int reg = 0; reg < 4; ++reg)
              Os[wave][reg][j * 16 + m] = f2bf(g ? acc1[j][reg] : acc0[j][reg]);
        }
#pragma unroll
        for (int rr = 0; rr < 4; ++rr) {
          int r = r0 + rowbase + g * 16 + p * 4 + rr;
          if (r < N)
            *(uint2*)&wout[(size_t)r * DIM + lane * 4] =
                *(const uint2*)&Os[wave][rr][lane * 4];
        }
      }
    }
  }
}

// per-type gemm (fallback path) — round-3 verified
__global__ __launch_bounds__(256, 2) void gemm_scores_kernel(
    const float* __restrict__ H, const unsigned short* __restrict__ Wt,
    const float* __restrict__ a, unsigned short* __restrict__ Whb,
    float* __restrict__ s_dst, float* __restrict__ s_src, int N) {
  __shared__ unsigned short Hs[64][264];
  __shared__ unsigned short Os[4][16][264];
  const int t = threadIdx.x;
  const int r0 = blockIdx.x * 64;
#pragma unroll
  for (int i = 0; i < 16; ++i) {
    int idx = t + i * 256;
    int row = idx >> 6;
    int c4 = idx & 63;
    int r = r0 + row;
    float4 h = (r < N) ? *(const float4*)&H[(size_t)r * DIM + c4 * 4]
                       : make_float4(0.f, 0.f, 0.f, 0.f);
    unsigned lo = (unsigned)f2bf(h.x) | ((unsigned)f2bf(h.y) << 16);
    unsigned hi = (unsigned)f2bf(h.z) | ((unsigned)f2bf(h.w) << 16);
    *(uint2*)&Hs[row][c4 * 4] = make_uint2(lo, hi);
  }
  __syncthreads();
  const int wave = t >> 6, lane = t & 63;
  const int q = lane >> 4, m = lane & 15;
  const int rowbase = wave * 16;
  short8 Af[8];
#pragma unroll
  for (int k0 = 0; k0 < 8; ++k0)
    Af[k0] = *(const short8*)&Hs[rowbase + m][k0 * 32 + q * 8];
  f32x4 acc[16];
#pragma unroll
  for (int j = 0; j < 16; ++j) acc[j] = (f32x4){0.f, 0.f, 0.f, 0.f};
#pragma unroll
  for (int k0 = 0; k0 < 8; ++k0) {
#pragma unroll
    for (int j = 0; j < 16; ++j) {
      short8 Bf = *(const short8*)&Wt[(size_t)(j * 16 + m) * DIM + k0 * 32 + q * 8];
      acc[j] = __builtin_amdgcn_mfma_f32_16x16x32_bf16(Af[k0], Bf, acc[j], 0, 0, 0);
    }
  }
  float pd[4] = {0, 0, 0, 0}, ps[4] = {0, 0, 0, 0};
#pragma unroll
  for (int j = 0; j < 16; ++j) {
    int col = j * 16 + m;
    float ad = a[col], as = a[DIM + col];
#pragma unroll
    for (int reg = 0; reg < 4; ++reg) {
      float v = acc[j][reg];
      pd[reg] += v * ad;
      ps[reg] += v * as;
      Os[wave][q * 4 + reg][col] = f2bf(v);
    }
  }
#pragma unroll
  for (int off = 8; off >= 1; off >>= 1) {
#pragma unroll
    for (int reg = 0; reg < 4; ++reg) {
      pd[reg] += __shfl_down(pd[reg], off);
      ps[reg] += __shfl_down(ps[reg], off);
    }
  }
  if (m == 0) {
#pragma unroll
    for (int reg = 0; reg < 4; ++reg) {
      int r = r0 + rowbase + q * 4 + reg;
      if (r < N) {
        s_dst[r] = pd[reg];
        s_src[r] = ps[reg];
      }
    }
  }
  __syncthreads();
#pragma unroll
  for (int row = 0; row < 16; ++row) {
    int r = r0 + rowbase + row;
    if (r < N)
      *(uint2*)&Whb[(size_t)r * DIM + lane * 4] = *(const uint2*)&Os[wave][row][lane * 4];
  }
}

// ---- CSR build via two-level bucket partition --------------------------------
__global__ __launch_bounds__(256) void bin_edges_kernel(
    const int* __restrict__ r0, const int* __restrict__ r1, const int* __restrict__ r2,
    const int* __restrict__ c0, const int* __restrict__ c1, const int* __restrict__ c2,
    int* __restrict__ bcnt,        // [3*NB], zero-initialized
    unsigned* __restrict__ pairs,  // [3*NB*SLOTS]
    int E, int NB) {
  __shared__ int hist[512];  // NB=391 <= 512
  __shared__ int curs[512];
  const int ty = blockIdx.y;
  const int* rr = ty == 0 ? r0 : (ty == 1 ? r1 : r2);
  const int* cc = ty == 0 ? c0 : (ty == 1 ? c1 : c2);
  const int t = threadIdx.x;
  const int base = blockIdx.x * TILE;
  for (int i = t; i < NB; i += 256) hist[i] = 0;
  __syncthreads();
  int rows[TILE / 256];
#pragma unroll
  for (int i = 0; i < TILE / 256; ++i) {
    int e = base + t + i * 256;
    int r = (e < E) ? rr[e] : -1;
    rows[i] = r;
    if (r >= 0) atomicAdd(&hist[r >> BSHIFT], 1);
  }
  __syncthreads();
  for (int b = t; b < NB; b += 256) {
    int h = hist[b];
    int off = h ? atomicAdd(&bcnt[ty * NB + b], h) : 0;
    curs[b] = b * SLOTS + off;  // absolute index within this type's slab
  }
  __syncthreads();
  unsigned* pt = pairs + (size_t)ty * NB * SLOTS;
#pragma unroll
  for (int i = 0; i < TILE / 256; ++i) {
    int e = base + t + i * 256;
    if (e >= E) continue;
    int r = rows[i];
    int b = r >> BSHIFT;
    int pos = atomicAdd(&curs[b], 1);
    if (pos - b * SLOTS < SLOTS)  // overflow guard (statistically unreachable)
      pt[pos] = ((unsigned)(r & 255) << 17) | (unsigned)cc[e];
  }
}

// Level 2: one block per (bucket,type). In-LDS counting sort (row key);
// emits rp/deg.
__global__ __launch_bounds__(256) void bucket_sort_kernel(
    const int* __restrict__ bcnt, unsigned* __restrict__ pairs,
    int* __restrict__ rp, int* __restrict__ deg, int N, int NB) {
  __shared__ int hist[256];
  __shared__ int excl[256];
  __shared__ int curs[256];
  __shared__ unsigned stage[SLOTS];
  const int b = blockIdx.x, ty = blockIdx.y;
  const int t = threadIdx.x;
  int cnt = bcnt[ty * NB + b];
  if (cnt > SLOTS) cnt = SLOTS;
  unsigned* pb = pairs + (size_t)ty * NB * SLOTS + (size_t)b * SLOTS;
  hist[t] = 0;
  __syncthreads();
  for (int i = t; i < cnt; i += 256) atomicAdd(&hist[pb[i] >> 17], 1);
  __syncthreads();
  int v = hist[t];
  excl[t] = v;
  __syncthreads();
  for (int off = 1; off < 256; off <<= 1) {
    int u = (t >= off) ? excl[t - off] : 0;
    __syncthreads();
    excl[t] += u;
    __syncthreads();
  }
  int ex = excl[t] - v;  // exclusive scan
  curs[t] = ex;
  int r = (b << BSHIFT) + t;
  if (r < N) {
    rp[(size_t)ty * N + r] = b * SLOTS + ex;
    deg[(size_t)ty * N + r] = v;
  }
  __syncthreads();
  for (int i = t; i < cnt; i += 256) {
    unsigned p = pb[i];
    int pos = atomicAdd(&curs[p >> 17], 1);
    stage[pos] = p;
  }
  __syncthreads();
  for (int i = t; i < cnt; i += 256) pb[i] = stage[i];
}

// FUSED gat (round-5 verified best): one wave per destination node, all 3
// types in-register, single out write (bias folded).
__global__ __launch_bounds__(256) void gat_fused_kernel(
    const int* __restrict__ rp, const int* __restrict__ deg,
    const unsigned* __restrict__ pairs,
    const float* __restrict__ s_dst, const float* __restrict__ s_src,
    const unsigned short* __restrict__ Whb,
    const float* __restrict__ bias, float* __restrict__ out, int N, int NB,
    size_t wstride) {
  __shared__ uint2 ebuf[4][64];  // per-wave parked (col, exp-weight)
  int n = (int)((blockIdx.x * (unsigned)blockDim.x + threadIdx.x) >> 6);
  if (n >= N) return;
  const int wid = (threadIdx.x >> 6);
  const int lane = threadIdx.x & 63;
  float4 total = {0.f, 0.f, 0.f, 0.f};
  for (int t = 0; t < 3; ++t) {
    int beg = rp[(size_t)t * N + n], d = deg[(size_t)t * N + n];
    if (d == 0) continue;
    int end = beg + d;
    const unsigned* pcol = pairs + (size_t)t * NB * SLOTS;
    const float* ss = s_src + (size_t)t * N;
    float sd = s_dst[(size_t)t * N + n];
    const unsigned short* wbase = Whb + (size_t)t * wstride + lane * 4;
    // pass A: segment max (lane-parallel)
    float mx = -__builtin_inff();
    for (int p = beg + lane; p < end; p += 64) {
      float v = sd + ss[pcol[p] & 0x1FFFFu];
      v = v > 0.f ? v : SLOPE * v;
      mx = fmaxf(mx, v);
    }
#pragma unroll
    for (int off = 32; off >= 1; off >>= 1) mx = fmaxf(mx, __shfl_down(mx, off));
    mx = __shfl(mx, 0);
    // pass B: chunk of 64 edges -> lane-parallel exp, then unrolled gather+FMA
    float4 acc = {0.f, 0.f, 0.f, 0.f};
    float psum = 0.f;
    for (int base = beg; base < end; base += 64) {
      int myp = base + lane;
      int cnt = end - base;
      if (cnt > 64) cnt = 64;
      unsigned myc = 0;
      float mype = 0.f;
      if (myp < end) {
        myc = pcol[myp] & 0x1FFFFu;
        float v = sd + ss[myc];
        v = v > 0.f ? v : SLOPE * v;
        mype = __expf(v - mx);
      }
      psum += mype;
      ebuf[wid][lane] = make_uint2(myc, __float_as_uint(mype));
      // same-wave LDS RAW: compiler inserts lgkmcnt; no barrier needed
#pragma unroll 8
      for (int j = 0; j < cnt; ++j) {
        uint2 cp = ebuf[wid][j];  // uniform addr: broadcast, conflict-free
        float pe = __uint_as_float(cp.y);
        ushort4 w = *(const ushort4*)&wbase[(size_t)cp.x * DIM];
        acc.x += pe * bf2f(w.x);
        acc.y += pe * bf2f(w.y);
        acc.z += pe * bf2f(w.z);
        acc.w += pe * bf2f(w.w);
      }
    }
#pragma unroll
    for (int off = 32; off >= 1; off >>= 1) psum += __shfl_down(psum, off);
    psum = __shfl(psum, 0);
    float inv = 1.f / fmaxf(psum, 1e-12f);
    total.x += acc.x * inv;
    total.y += acc.y * inv;
    total.z += acc.z * inv;
    total.w += acc.w * inv;
  }
  float4 cur = ((const float4*)bias)[lane];
  cur.x += total.x;
  cur.y += total.y;
  cur.z += total.z;
  cur.w += total.w;
  *((float4*)(out + (size_t)n * DIM) + lane) = cur;
}

// per-type kernel (fallback path when workspace is small) — round-3 verified
__global__ __launch_bounds__(256) void gat_node_kernel(
    const int* __restrict__ rp, const int* __restrict__ deg,
    const unsigned* __restrict__ pcol,
    const float* __restrict__ s_dst, const float* __restrict__ s_src,
    const unsigned short* __restrict__ Whb,
    const float* __restrict__ bias, float* __restrict__ out, int N, int first) {
  __shared__ uint2 ebuf[4][64];
  int n = (int)((blockIdx.x * (unsigned)blockDim.x + threadIdx.x) >> 6);
  if (n >= N) return;
  const int wid = (threadIdx.x >> 6);
  const int lane = threadIdx.x & 63;
  int beg = rp[n], d = deg[n], end = beg + d;
  if (!first && d == 0) return;
  float sd = s_dst[n];
  float mx = -__builtin_inff();
  for (int p = beg + lane; p < end; p += 64) {
    float v = sd + s_src[pcol[p] & 0x1FFFFu];
    v = v > 0.f ? v : SLOPE * v;
    mx = fmaxf(mx, v);
  }
#pragma unroll
  for (int off = 32; off >= 1; off >>= 1) mx = fmaxf(mx, __shfl_down(mx, off));
  mx = __shfl(mx, 0);
  const unsigned short* wbase = Whb + lane * 4;
  float4 acc = {0.f, 0.f, 0.f, 0.f};
  float psum = 0.f;
  for (int base = beg; base < end; base += 64) {
    int myp = base + lane;
    int cnt = end - base;
    if (cnt > 64) cnt = 64;
    unsigned myc = 0;
    float mype = 0.f;
    if (myp < end) {
      myc = pcol[myp] & 0x1FFFFu;
      float v = sd + s_src[myc];
      v = v > 0.f ? v : SLOPE * v;
      mype = __expf(v - mx);
    }
    psum += mype;
    ebuf[wid][lane] = make_uint2(myc, __float_as_uint(mype));
#pragma unroll 8
    for (int j = 0; j < cnt; ++j) {
      uint2 cp = ebuf[wid][j];
      float pe = __uint_as_float(cp.y);
      ushort4 w = *(const ushort4*)&wbase[(size_t)cp.x * DIM];
      acc.x += pe * bf2f(w.x);
      acc.y += pe * bf2f(w.y);
      acc.z += pe * bf2f(w.z);
      acc.w += pe * bf2f(w.w);
    }
  }
#pragma unroll
  for (int off = 32; off >= 1; off >>= 1) psum += __shfl_down(psum, off);
  psum = __shfl(psum, 0);
  float inv = 1.f / fmaxf(psum, 1e-12f);
  float4* o = (float4*)(out + (size_t)n * DIM) + lane;
  float4 cur = first ? ((const float4*)bias)[lane] : *o;
  cur.x += acc.x * inv;
  cur.y += acc.y * inv;
  cur.z += acc.z * inv;
  cur.w += acc.w * inv;
  *o = cur;
}

static inline size_t align256(size_t x) { return (x + 255) & ~(size_t)255; }

extern "C" void kernel_launch(void* const* d_in, const int* in_sizes, int n_in,
                              void* d_out, int out_size, void* d_ws, size_t ws_size,
                              hipStream_t stream) {
  const float* H = (const float*)d_in[0];
  const float* W[3] = {(const float*)d_in[1], (const float*)d_in[2], (const float*)d_in[3]};
  const float* a[3] = {(const float*)d_in[4], (const float*)d_in[5], (const float*)d_in[6]};
  const float* bias = (const float*)d_in[7];
  const int* row[3] = {(const int*)d_in[8], (const int*)d_in[10], (const int*)d_in[12]};
  const int* col[3] = {(const int*)d_in[9], (const int*)d_in[11], (const int*)d_in[13]};
  const int N = in_sizes[0] / DIM;
  const int E = in_sizes[8];
  const int NB = (N + 255) >> BSHIFT;  // 391 for N=100000 (must be <= 512)
  float* out = (float*)d_out;

  // workspace layout: fixed part first, Whb (1x or 3x) last
  char* ws = (char*)d_ws;
  size_t off = 0;
  unsigned short* Wt = (unsigned short*)(ws + off);
  off = align256(off + (size_t)3 * DIM * DIM * sizeof(unsigned short));
  float* s_dst = (float*)(ws + off);  // [3][N]
  off = align256(off + (size_t)3 * N * sizeof(float));
  float* s_src = (float*)(ws + off);  // [3][N]
  off = align256(off + (size_t)3 * N * sizeof(float));
  int* bcnt = (int*)(ws + off);
  off = align256(off + (size_t)3 * NB * sizeof(int));
  int* rp = (int*)(ws + off);
  off = align256(off + (size_t)3 * N * sizeof(int));
  int* deg = (int*)(ws + off);
  off = align256(off + (size_t)3 * N * sizeof(int));
  unsigned* pairs = (unsigned*)(ws + off);
  off = align256(off + (size_t)3 * NB * SLOTS * sizeof(unsigned));
  unsigned short* Whb = (unsigned short*)(ws + off);
  const size_t whb_bytes = align256((size_t)N * DIM * sizeof(unsigned short));
  const size_t wstride = whb_bytes / sizeof(unsigned short);
  const int fused = (ws_size >= off + 3 * whb_bytes) ? 1 : 0;

  wtrans_kernel<<<dim3(DIM, 3), 256, 0, stream>>>(W[0], W[1], W[2], Wt);
  hipMemsetAsync(bcnt, 0, (size_t)3 * NB * sizeof(int), stream);
  const int eb = (E + TILE - 1) / TILE;
  bin_edges_kernel<<<dim3(eb, 3), 256, 0, stream>>>(row[0], row[1], row[2], col[0], col[1],
                                                    col[2], bcnt, pairs, E, NB);
  bucket_sort_kernel<<<dim3(NB, 3), 256, 0, stream>>>(bcnt, pairs, rp, deg, N, NB);

  const int gat_blocks = (N * 64 + 255) / 256;
  if (fused) {
    gemm3_scores_kernel<<<(N + 127) / 128, 256, 0, stream>>>(H, Wt, a[0], a[1], a[2], Whb,
                                                             s_dst, s_src, N, wstride);
    gat_fused_kernel<<<gat_blocks, 256, 0, stream>>>(rp, deg, pairs, s_dst, s_src, Whb, bias,
                                                     out, N, NB, wstride);
  } else {
    for (int t = 0; t < 3; ++t) {
      gemm_scores_kernel<<<(N + 63) / 64, 256, 0, stream>>>(H, Wt + (size_t)t * DIM * DIM,
                                                            a[t], Whb, s_dst + (size_t)t * N,
                                                            s_src + (size_t)t * N, N);
      gat_node_kernel<<<gat_blocks, 256, 0, stream>>>(
          rp + (size_t)t * N, deg + (size_t)t * N, pairs + (size_t)t * NB * SLOTS,
          s_dst + (size_t)t * N, s_src + (size_t)t * N, Whb, bias, out, N, t == 0 ? 1 : 0);
    }
  }
  (void)n_in;
  (void)out_size;
  (void)ws_size;
}

// Round 10
// 1387.393 us; speedup vs baseline: 1.1167x; 1.0277x over previous
//
#include <hip/hip_runtime.h>
#include <cstdint>
#include <cstddef>

#define DIM 256
#define SLOPE 0.2f
#define BSHIFT 8          // 256 rows per bucket
#define SLOTS 9216        // per-bucket capacity: mean 8192 + ~11 sigma slack
#define TILE 4096         // edges per bin_edges block

typedef __attribute__((ext_vector_type(8))) short short8;  // 8 bf16 (4 VGPRs)
typedef __attribute__((ext_vector_type(4))) float f32x4;   // 4 fp32 acc

__device__ __forceinline__ unsigned short f2bf(float f) {  // RNE fp32->bf16
  unsigned u = __float_as_uint(f);
  u += 0x7fffu + ((u >> 16) & 1u);
  return (unsigned short)(u >> 16);
}
__device__ __forceinline__ float bf2f(unsigned short h) {
  return __uint_as_float(((unsigned)h) << 16);
}

// ---------------- bodies (shared by standalone + über kernels) ---------------

// bin_edges: bin one TILE of edges into 256-row bucket slabs.
__device__ __forceinline__ void bin_edges_body(
    int bx, int ty, int* hist, int* curs, const int* __restrict__ rr,
    const int* __restrict__ cc, int* __restrict__ bcnt, unsigned* __restrict__ pairs,
    int E, int NB) {
  const int t = threadIdx.x;
  const int base = bx * TILE;
  for (int i = t; i < NB; i += 256) hist[i] = 0;
  __syncthreads();
  int rows[TILE / 256];
#pragma unroll
  for (int i = 0; i < TILE / 256; ++i) {
    int e = base + t + i * 256;
    int r = (e < E) ? rr[e] : -1;
    rows[i] = r;
    if (r >= 0) atomicAdd(&hist[r >> BSHIFT], 1);
  }
  __syncthreads();
  for (int b = t; b < NB; b += 256) {
    int h = hist[b];
    int off = h ? atomicAdd(&bcnt[ty * NB + b], h) : 0;
    curs[b] = b * SLOTS + off;  // absolute index within this type's slab
  }
  __syncthreads();
  unsigned* pt = pairs + (size_t)ty * NB * SLOTS;
#pragma unroll
  for (int i = 0; i < TILE / 256; ++i) {
    int e = base + t + i * 256;
    if (e >= E) continue;
    int r = rows[i];
    int b = r >> BSHIFT;
    int pos = atomicAdd(&curs[b], 1);
    if (pos - b * SLOTS < SLOTS)  // overflow guard (statistically unreachable)
      pt[pos] = ((unsigned)(r & 255) << 17) | (unsigned)cc[e];
  }
}

// bucket_sort: in-LDS counting sort of one (bucket,type) slab; emits rp/deg.
__device__ __forceinline__ void bsort_body(
    int b, int ty, char* smem, const int* __restrict__ bcnt,
    unsigned* __restrict__ pairs, int* __restrict__ rp, int* __restrict__ deg,
    int N, int NB) {
  int* hist = (int*)smem;
  int* excl = hist + 256;
  int* curs = excl + 256;
  unsigned* stage = (unsigned*)(curs + 256);  // 36864 B
  const int t = threadIdx.x;
  int cnt = bcnt[ty * NB + b];
  if (cnt > SLOTS) cnt = SLOTS;
  unsigned* pb = pairs + (size_t)ty * NB * SLOTS + (size_t)b * SLOTS;
  hist[t] = 0;
  __syncthreads();
  for (int i = t; i < cnt; i += 256) atomicAdd(&hist[pb[i] >> 17], 1);
  __syncthreads();
  int v = hist[t];
  excl[t] = v;
  __syncthreads();
  for (int off = 1; off < 256; off <<= 1) {
    int u = (t >= off) ? excl[t - off] : 0;
    __syncthreads();
    excl[t] += u;
    __syncthreads();
  }
  int ex = excl[t] - v;  // exclusive scan
  curs[t] = ex;
  int r = (b << BSHIFT) + t;
  if (r < N) {
    rp[(size_t)ty * N + r] = b * SLOTS + ex;
    deg[(size_t)ty * N + r] = v;
  }
  __syncthreads();
  for (int i = t; i < cnt; i += 256) {
    unsigned p = pb[i];
    int pos = atomicAdd(&curs[p >> 17], 1);
    stage[pos] = p;
  }
  __syncthreads();
  for (int i = t; i < cnt; i += 256) pb[i] = stage[i];
}

// gemm3 v2 body: 128-row tile, 4 waves x 32 rows/wave, 2 MFMA per B-load.
__device__ __forceinline__ void gemm3_body(
    int bx, char* smem, const float* __restrict__ H, const unsigned short* __restrict__ Wt,
    const float* __restrict__ a0, const float* __restrict__ a1,
    const float* __restrict__ a2, unsigned short* __restrict__ Whb,
    float* __restrict__ s_dst, float* __restrict__ s_src, int N, size_t wstride) {
  unsigned short(*Hs)[264] = (unsigned short(*)[264])smem;             // 128x264
  unsigned short(*Os)[4][264] = (unsigned short(*)[4][264])(smem + 128 * 264 * 2);
  const int t = threadIdx.x;
  const int r0 = bx * 128;
#pragma unroll
  for (int i = 0; i < 32; ++i) {
    int idx = t + i * 256;
    int row = idx >> 6;
    int c4 = idx & 63;
    int r = r0 + row;
    float4 h = (r < N) ? *(const float4*)&H[(size_t)r * DIM + c4 * 4]
                       : make_float4(0.f, 0.f, 0.f, 0.f);
    unsigned lo = (unsigned)f2bf(h.x) | ((unsigned)f2bf(h.y) << 16);
    unsigned hi = (unsigned)f2bf(h.z) | ((unsigned)f2bf(h.w) << 16);
    *(uint2*)&Hs[row][c4 * 4] = make_uint2(lo, hi);
  }
  __syncthreads();
  const int wave = t >> 6, lane = t & 63;
  const int q = lane >> 4, m = lane & 15;
  const int rowbase = wave * 32;
  short8 Af0[8], Af1[8];
#pragma unroll
  for (int k0 = 0; k0 < 8; ++k0) {
    Af0[k0] = *(const short8*)&Hs[rowbase + m][k0 * 32 + q * 8];
    Af1[k0] = *(const short8*)&Hs[rowbase + 16 + m][k0 * 32 + q * 8];
  }
  const float* aptr[3] = {a0, a1, a2};
  for (int ty = 0; ty < 3; ++ty) {
    const unsigned short* Wtt = Wt + (size_t)ty * DIM * DIM;
    const float* a = aptr[ty];
    f32x4 acc0[16], acc1[16];
#pragma unroll
    for (int j = 0; j < 16; ++j) {
      acc0[j] = (f32x4){0.f, 0.f, 0.f, 0.f};
      acc1[j] = (f32x4){0.f, 0.f, 0.f, 0.f};
    }
#pragma unroll
    for (int k0 = 0; k0 < 8; ++k0) {
#pragma unroll
      for (int j = 0; j < 16; ++j) {
        short8 Bf = *(const short8*)&Wtt[(size_t)(j * 16 + m) * DIM + k0 * 32 + q * 8];
        acc0[j] = __builtin_amdgcn_mfma_f32_16x16x32_bf16(Af0[k0], Bf, acc0[j], 0, 0, 0);
        acc1[j] = __builtin_amdgcn_mfma_f32_16x16x32_bf16(Af1[k0], Bf, acc1[j], 0, 0, 0);
      }
    }
    float pd0[4] = {0, 0, 0, 0}, ps0[4] = {0, 0, 0, 0};
    float pd1[4] = {0, 0, 0, 0}, ps1[4] = {0, 0, 0, 0};
#pragma unroll
    for (int j = 0; j < 16; ++j) {
      int col = j * 16 + m;
      float ad = a[col], as = a[DIM + col];
#pragma unroll
      for (int reg = 0; reg < 4; ++reg) {
        float v0 = acc0[j][reg], v1 = acc1[j][reg];
        pd0[reg] += v0 * ad;
        ps0[reg] += v0 * as;
        pd1[reg] += v1 * ad;
        ps1[reg] += v1 * as;
      }
    }
#pragma unroll
    for (int off = 8; off >= 1; off >>= 1) {
#pragma unroll
      for (int reg = 0; reg < 4; ++reg) {
        pd0[reg] += __shfl_down(pd0[reg], off);
        ps0[reg] += __shfl_down(ps0[reg], off);
        pd1[reg] += __shfl_down(pd1[reg], off);
        ps1[reg] += __shfl_down(ps1[reg], off);
      }
    }
    if (m == 0) {
#pragma unroll
      for (int reg = 0; reg < 4; ++reg) {
        int ra = r0 + rowbase + q * 4 + reg;
        int rb = ra + 16;
        if (ra < N) {
          s_dst[(size_t)ty * N + ra] = pd0[reg];
          s_src[(size_t)ty * N + ra] = ps0[reg];
        }
        if (rb < N) {
          s_dst[(size_t)ty * N + rb] = pd1[reg];
          s_src[(size_t)ty * N + rb] = ps1[reg];
        }
      }
    }
    // Whb stores in 4-row passes (Os is wave-private: same-wave LDS ordering)
    unsigned short* wout = Whb + (size_t)ty * wstride;
#pragma unroll
    for (int g = 0; g < 2; ++g) {
#pragma unroll
      for (int p = 0; p < 4; ++p) {
        if (q == p) {
#pragma unroll
          for (int j = 0; j < 16; ++j)
#pragma unroll
            for (int reg = 0; reg < 4; ++reg)
              Os[wave][reg][j * 16 + m] = f2bf(g ? acc1[j][reg] : acc0[j][reg]);
        }
#pragma unroll
        for (int rr = 0; rr < 4; ++rr) {
          int r = r0 + rowbase + g * 16 + p * 4 + rr;
          if (r < N)
            *(uint2*)&wout[(size_t)r * DIM + lane * 4] =
                *(const uint2*)&Os[wave][rr][lane * 4];
        }
      }
    }
  }
}

// ---------------- über kernels ----------------

// überA: wtrans (768 blocks) ∥ bin_edges (3*eb blocks) — independent work.
__global__ __launch_bounds__(256) void prep_kernel(
    const float* __restrict__ W0, const float* __restrict__ W1,
    const float* __restrict__ W2, unsigned short* __restrict__ Wt,
    const int* __restrict__ r0, const int* __restrict__ r1, const int* __restrict__ r2,
    const int* __restrict__ c0, const int* __restrict__ c1, const int* __restrict__ c2,
    int* __restrict__ bcnt, unsigned* __restrict__ pairs, int E, int NB, int eb) {
  __shared__ int smem[1024];  // hist 512 + curs 512
  const int bx = blockIdx.x;
  if (bx < 768) {  // wtrans: bx = ty*256 + k
    int ty = bx >> 8, k = bx & 255, n = threadIdx.x;
    const float* W = ty == 0 ? W0 : (ty == 1 ? W1 : W2);
    Wt[((size_t)ty * DIM + n) * DIM + k] = f2bf(W[k * DIM + n]);
    return;
  }
  int e2 = bx - 768;
  int ty = e2 / eb, bxx = e2 % eb;
  const int* rr = ty == 0 ? r0 : (ty == 1 ? r1 : r2);
  const int* cc = ty == 0 ? c0 : (ty == 1 ? c1 : c2);
  bin_edges_body(bxx, ty, smem, smem + 512, rr, cc, bcnt, pairs, E, NB);
}

// überB: gemm3 (gemm_blocks) ∥ bucket_sort (3*NB blocks) — independent work.
// Shared-mem union: gemm3 needs 76032 B, bucket_sort 39936 B.
__global__ __launch_bounds__(256, 2) void compute_kernel(
    const float* __restrict__ H, const unsigned short* __restrict__ Wt,
    const float* __restrict__ a0, const float* __restrict__ a1,
    const float* __restrict__ a2, unsigned short* __restrict__ Whb,
    float* __restrict__ s_dst, float* __restrict__ s_src, int N, size_t wstride,
    const int* __restrict__ bcnt, unsigned* __restrict__ pairs,
    int* __restrict__ rp, int* __restrict__ deg, int NB, int gemm_blocks) {
  __shared__ __align__(16) char smem[76032];
  const int bx = blockIdx.x;
  if (bx < gemm_blocks) {
    gemm3_body(bx, smem, H, Wt, a0, a1, a2, Whb, s_dst, s_src, N, wstride);
  } else {
    int e = bx - gemm_blocks;
    bsort_body(e % NB, e / NB, smem, bcnt, pairs, rp, deg, N, NB);
  }
}

// standalone bucket_sort (fallback path)
__global__ __launch_bounds__(256) void bucket_sort_kernel(
    const int* __restrict__ bcnt, unsigned* __restrict__ pairs,
    int* __restrict__ rp, int* __restrict__ deg, int N, int NB) {
  __shared__ __align__(16) char smem[39936];
  bsort_body(blockIdx.x, blockIdx.y, smem, bcnt, pairs, rp, deg, N, NB);
}

// per-type gemm (fallback path) — round-3 verified
__global__ __launch_bounds__(256, 2) void gemm_scores_kernel(
    const float* __restrict__ H, const unsigned short* __restrict__ Wt,
    const float* __restrict__ a, unsigned short* __restrict__ Whb,
    float* __restrict__ s_dst, float* __restrict__ s_src, int N) {
  __shared__ unsigned short Hs[64][264];
  __shared__ unsigned short Os[4][16][264];
  const int t = threadIdx.x;
  const int r0 = blockIdx.x * 64;
#pragma unroll
  for (int i = 0; i < 16; ++i) {
    int idx = t + i * 256;
    int row = idx >> 6;
    int c4 = idx & 63;
    int r = r0 + row;
    float4 h = (r < N) ? *(const float4*)&H[(size_t)r * DIM + c4 * 4]
                       : make_float4(0.f, 0.f, 0.f, 0.f);
    unsigned lo = (unsigned)f2bf(h.x) | ((unsigned)f2bf(h.y) << 16);
    unsigned hi = (unsigned)f2bf(h.z) | ((unsigned)f2bf(h.w) << 16);
    *(uint2*)&Hs[row][c4 * 4] = make_uint2(lo, hi);
  }
  __syncthreads();
  const int wave = t >> 6, lane = t & 63;
  const int q = lane >> 4, m = lane & 15;
  const int rowbase = wave * 16;
  short8 Af[8];
#pragma unroll
  for (int k0 = 0; k0 < 8; ++k0)
    Af[k0] = *(const short8*)&Hs[rowbase + m][k0 * 32 + q * 8];
  f32x4 acc[16];
#pragma unroll
  for (int j = 0; j < 16; ++j) acc[j] = (f32x4){0.f, 0.f, 0.f, 0.f};
#pragma unroll
  for (int k0 = 0; k0 < 8; ++k0) {
#pragma unroll
    for (int j = 0; j < 16; ++j) {
      short8 Bf = *(const short8*)&Wt[(size_t)(j * 16 + m) * DIM + k0 * 32 + q * 8];
      acc[j] = __builtin_amdgcn_mfma_f32_16x16x32_bf16(Af[k0], Bf, acc[j], 0, 0, 0);
    }
  }
  float pd[4] = {0, 0, 0, 0}, ps[4] = {0, 0, 0, 0};
#pragma unroll
  for (int j = 0; j < 16; ++j) {
    int col = j * 16 + m;
    float ad = a[col], as = a[DIM + col];
#pragma unroll
    for (int reg = 0; reg < 4; ++reg) {
      float v = acc[j][reg];
      pd[reg] += v * ad;
      ps[reg] += v * as;
      Os[wave][q * 4 + reg][col] = f2bf(v);
    }
  }
#pragma unroll
  for (int off = 8; off >= 1; off >>= 1) {
#pragma unroll
    for (int reg = 0; reg < 4; ++reg) {
      pd[reg] += __shfl_down(pd[reg], off);
      ps[reg] += __shfl_down(ps[reg], off);
    }
  }
  if (m == 0) {
#pragma unroll
    for (int reg = 0; reg < 4; ++reg) {
      int r = r0 + rowbase + q * 4 + reg;
      if (r < N) {
        s_dst[r] = pd[reg];
        s_src[r] = ps[reg];
      }
    }
  }
  __syncthreads();
#pragma unroll
  for (int row = 0; row < 16; ++row) {
    int r = r0 + rowbase + row;
    if (r < N)
      *(uint2*)&Whb[(size_t)r * DIM + lane * 4] = *(const uint2*)&Os[wave][row][lane * 4];
  }
}

// FUSED gat (round-5 verified best): one wave per destination node, all 3
// types in-register, single out write (bias folded).
__global__ __launch_bounds__(256) void gat_fused_kernel(
    const int* __restrict__ rp, const int* __restrict__ deg,
    const unsigned* __restrict__ pairs,
    const float* __restrict__ s_dst, const float* __restrict__ s_src,
    const unsigned short* __restrict__ Whb,
    const float* __restrict__ bias, float* __restrict__ out, int N, int NB,
    size_t wstride) {
  __shared__ uint2 ebuf[4][64];  // per-wave parked (col, exp-weight)
  int n = (int)((blockIdx.x * (unsigned)blockDim.x + threadIdx.x) >> 6);
  if (n >= N) return;
  const int wid = (threadIdx.x >> 6);
  const int lane = threadIdx.x & 63;
  float4 total = {0.f, 0.f, 0.f, 0.f};
  for (int t = 0; t < 3; ++t) {
    int beg = rp[(size_t)t * N + n], d = deg[(size_t)t * N + n];
    if (d == 0) continue;
    int end = beg + d;
    const unsigned* pcol = pairs + (size_t)t * NB * SLOTS;
    const float* ss = s_src + (size_t)t * N;
    float sd = s_dst[(size_t)t * N + n];
    const unsigned short* wbase = Whb + (size_t)t * wstride + lane * 4;
    // pass A: segment max (lane-parallel)
    float mx = -__builtin_inff();
    for (int p = beg + lane; p < end; p += 64) {
      float v = sd + ss[pcol[p] & 0x1FFFFu];
      v = v > 0.f ? v : SLOPE * v;
      mx = fmaxf(mx, v);
    }
#pragma unroll
    for (int off = 32; off >= 1; off >>= 1) mx = fmaxf(mx, __shfl_down(mx, off));
    mx = __shfl(mx, 0);
    // pass B: chunk of 64 edges -> lane-parallel exp, then unrolled gather+FMA
    float4 acc = {0.f, 0.f, 0.f, 0.f};
    float psum = 0.f;
    for (int base = beg; base < end; base += 64) {
      int myp = base + lane;
      int cnt = end - base;
      if (cnt > 64) cnt = 64;
      unsigned myc = 0;
      float mype = 0.f;
      if (myp < end) {
        myc = pcol[myp] & 0x1FFFFu;
        float v = sd + ss[myc];
        v = v > 0.f ? v : SLOPE * v;
        mype = __expf(v - mx);
      }
      psum += mype;
      ebuf[wid][lane] = make_uint2(myc, __float_as_uint(mype));
      // same-wave LDS RAW: compiler inserts lgkmcnt; no barrier needed
#pragma unroll 8
      for (int j = 0; j < cnt; ++j) {
        uint2 cp = ebuf[wid][j];  // uniform addr: broadcast, conflict-free
        float pe = __uint_as_float(cp.y);
        ushort4 w = *(const ushort4*)&wbase[(size_t)cp.x * DIM];
        acc.x += pe * bf2f(w.x);
        acc.y += pe * bf2f(w.y);
        acc.z += pe * bf2f(w.z);
        acc.w += pe * bf2f(w.w);
      }
    }
#pragma unroll
    for (int off = 32; off >= 1; off >>= 1) psum += __shfl_down(psum, off);
    psum = __shfl(psum, 0);
    float inv = 1.f / fmaxf(psum, 1e-12f);
    total.x += acc.x * inv;
    total.y += acc.y * inv;
    total.z += acc.z * inv;
    total.w += acc.w * inv;
  }
  float4 cur = ((const float4*)bias)[lane];
  cur.x += total.x;
  cur.y += total.y;
  cur.z += total.z;
  cur.w += total.w;
  *((float4*)(out + (size_t)n * DIM) + lane) = cur;
}

// per-type gat (fallback path when workspace is small) — round-3 verified
__global__ __launch_bounds__(256) void gat_node_kernel(
    const int* __restrict__ rp, const int* __restrict__ deg,
    const unsigned* __restrict__ pcol,
    const float* __restrict__ s_dst, const float* __restrict__ s_src,
    const unsigned short* __restrict__ Whb,
    const float* __restrict__ bias, float* __restrict__ out, int N, int first) {
  __shared__ uint2 ebuf[4][64];
  int n = (int)((blockIdx.x * (unsigned)blockDim.x + threadIdx.x) >> 6);
  if (n >= N) return;
  const int wid = (threadIdx.x >> 6);
  const int lane = threadIdx.x & 63;
  int beg = rp[n], d = deg[n], end = beg + d;
  if (!first && d == 0) return;
  float sd = s_dst[n];
  float mx = -__builtin_inff();
  for (int p = beg + lane; p < end; p += 64) {
    float v = sd + s_src[pcol[p] & 0x1FFFFu];
    v = v > 0.f ? v : SLOPE * v;
    mx = fmaxf(mx, v);
  }
#pragma unroll
  for (int off = 32; off >= 1; off >>= 1) mx = fmaxf(mx, __shfl_down(mx, off));
  mx = __shfl(mx, 0);
  const unsigned short* wbase = Whb + lane * 4;
  float4 acc = {0.f, 0.f, 0.f, 0.f};
  float psum = 0.f;
  for (int base = beg; base < end; base += 64) {
    int myp = base + lane;
    int cnt = end - base;
    if (cnt > 64) cnt = 64;
    unsigned myc = 0;
    float mype = 0.f;
    if (myp < end) {
      myc = pcol[myp] & 0x1FFFFu;
      float v = sd + s_src[myc];
      v = v > 0.f ? v : SLOPE * v;
      mype = __expf(v - mx);
    }
    psum += mype;
    ebuf[wid][lane] = make_uint2(myc, __float_as_uint(mype));
#pragma unroll 8
    for (int j = 0; j < cnt; ++j) {
      uint2 cp = ebuf[wid][j];
      float pe = __uint_as_float(cp.y);
      ushort4 w = *(const ushort4*)&wbase[(size_t)cp.x * DIM];
      acc.x += pe * bf2f(w.x);
      acc.y += pe * bf2f(w.y);
      acc.z += pe * bf2f(w.z);
      acc.w += pe * bf2f(w.w);
    }
  }
#pragma unroll
  for (int off = 32; off >= 1; off >>= 1) psum += __shfl_down(psum, off);
  psum = __shfl(psum, 0);
  float inv = 1.f / fmaxf(psum, 1e-12f);
  float4* o = (float4*)(out + (size_t)n * DIM) + lane;
  float4 cur = first ? ((const float4*)bias)[lane] : *o;
  cur.x += acc.x * inv;
  cur.y += acc.y * inv;
  cur.z += acc.z * inv;
  cur.w += acc.w * inv;
  *o = cur;
}

static inline size_t align256(size_t x) { return (x + 255) & ~(size_t)255; }

extern "C" void kernel_launch(void* const* d_in, const int* in_sizes, int n_in,
                              void* d_out, int out_size, void* d_ws, size_t ws_size,
                              hipStream_t stream) {
  const float* H = (const float*)d_in[0];
  const float* W[3] = {(const float*)d_in[1], (const float*)d_in[2], (const float*)d_in[3]};
  const float* a[3] = {(const float*)d_in[4], (const float*)d_in[5], (const float*)d_in[6]};
  const float* bias = (const float*)d_in[7];
  const int* row[3] = {(const int*)d_in[8], (const int*)d_in[10], (const int*)d_in[12]};
  const int* col[3] = {(const int*)d_in[9], (const int*)d_in[11], (const int*)d_in[13]};
  const int N = in_sizes[0] / DIM;
  const int E = in_sizes[8];
  const int NB = (N + 255) >> BSHIFT;  // 391 for N=100000 (must be <= 512)
  float* out = (float*)d_out;

  // workspace layout: fixed part first, Whb (1x or 3x) last
  char* ws = (char*)d_ws;
  size_t off = 0;
  unsigned short* Wt = (unsigned short*)(ws + off);
  off = align256(off + (size_t)3 * DIM * DIM * sizeof(unsigned short));
  float* s_dst = (float*)(ws + off);  // [3][N]
  off = align256(off + (size_t)3 * N * sizeof(float));
  float* s_src = (float*)(ws + off);  // [3][N]
  off = align256(off + (size_t)3 * N * sizeof(float));
  int* bcnt = (int*)(ws + off);
  off = align256(off + (size_t)3 * NB * sizeof(int));
  int* rp = (int*)(ws + off);
  off = align256(off + (size_t)3 * N * sizeof(int));
  int* deg = (int*)(ws + off);
  off = align256(off + (size_t)3 * N * sizeof(int));
  unsigned* pairs = (unsigned*)(ws + off);
  off = align256(off + (size_t)3 * NB * SLOTS * sizeof(unsigned));
  unsigned short* Whb = (unsigned short*)(ws + off);
  const size_t whb_bytes = align256((size_t)N * DIM * sizeof(unsigned short));
  const size_t wstride = whb_bytes / sizeof(unsigned short);
  const int fused = (ws_size >= off + 3 * whb_bytes) ? 1 : 0;

  const int eb = (E + TILE - 1) / TILE;
  hipMemsetAsync(bcnt, 0, (size_t)3 * NB * sizeof(int), stream);
  // überA: wtrans ∥ bin_edges
  prep_kernel<<<768 + 3 * eb, 256, 0, stream>>>(W[0], W[1], W[2], Wt, row[0], row[1], row[2],
                                                col[0], col[1], col[2], bcnt, pairs, E, NB, eb);

  const int gat_blocks = (N * 64 + 255) / 256;
  if (fused) {
    // überB: gemm3 ∥ bucket_sort
    const int gemm_blocks = (N + 127) / 128;
    compute_kernel<<<gemm_blocks + 3 * NB, 256, 0, stream>>>(
        H, Wt, a[0], a[1], a[2], Whb, s_dst, s_src, N, wstride, bcnt, pairs, rp, deg, NB,
        gemm_blocks);
    gat_fused_kernel<<<gat_blocks, 256, 0, stream>>>(rp, deg, pairs, s_dst, s_src, Whb, bias,
                                                     out, N, NB, wstride);
  } else {
    bucket_sort_kernel<<<dim3(NB, 3), 256, 0, stream>>>(bcnt, pairs, rp, deg, N, NB);
    for (int t = 0; t < 3; ++t) {
      gemm_scores_kernel<<<(N + 63) / 64, 256, 0, stream>>>(H, Wt + (size_t)t * DIM * DIM,
                                                            a[t], Whb, s_dst + (size_t)t * N,
                                                            s_src + (size_t)t * N, N);
      gat_node_kernel<<<gat_blocks, 256, 0, stream>>>(
          rp + (size_t)t * N, deg + (size_t)t * N, pairs + (size_t)t * NB * SLOTS,
          s_dst + (size_t)t * N, s_src + (size_t)t * N, Whb, bias, out, N, t == 0 ? 1 : 0);
    }
  }
  (void)n_in;
  (void)out_size;
  (void)ws_size;
}